// Round 5
// baseline (657.515 us; speedup 1.0000x reference)
//
#include <hip/hip_runtime.h>
#include <hip/hip_bf16.h>

#define NN 4096
#define EE 2048
#define RR 4
#define FF 128
#define HDD 256

typedef __attribute__((ext_vector_type(4))) float floatx4;
typedef __attribute__((ext_vector_type(8))) __bf16 bf16x8;

#define AS1 __attribute__((address_space(1)))
#define AS3 __attribute__((address_space(3)))

__device__ __forceinline__ void async16(const void* g, void* l) {
  // global -> LDS direct copy, 16B per lane; LDS dest = wave-uniform base + lane*16
  __builtin_amdgcn_global_load_lds((const AS1 void*)(unsigned long long)(g),
                                   (AS3 void*)(unsigned int)(unsigned long long)(l),
                                   16, 0, 0);
}

__device__ inline unsigned short f2b(float x) {
  unsigned int u = __float_as_uint(x);
  unsigned int r = u + 0x7fffu + ((u >> 16) & 1u);
  return (unsigned short)(r >> 16);
}

// ---------------- prep: softmax(rel_attn), sigmoid(imp) ----------------
__global__ void k_prep(const float* rel, const float* imp, float* rw, float* sig) {
  if (threadIdx.x == 0) {
    float m = -1e30f;
    for (int r = 0; r < RR; r++) m = fmaxf(m, rel[r]);
    float e[RR], s = 0.f;
    for (int r = 0; r < RR; r++) { e[r] = expf(rel[r] - m); s += e[r]; }
    for (int r = 0; r < RR; r++) rw[r] = e[r] / s;
    for (int i = 0; i < 3 * RR; i++) sig[i] = 1.0f / (1.0f + expf(-imp[i]));
  }
}

// ---- single pass over H: row sums -> dvs[r][n] = rw*rsqrt(rw*sum+eps), plus 0/1 bitmask ----
__global__ void k_dvmask(const float* __restrict__ H, const float* __restrict__ rw,
                         float* __restrict__ dvs, unsigned long long* __restrict__ mask) {
  int wave = (blockIdx.x << 2) | (threadIdx.x >> 6);  // = r*NN + n
  int lane = threadIdx.x & 63;
  int r = wave >> 12;
  const float* row = H + (size_t)wave * EE;
  unsigned long long* mrow = mask + (size_t)wave * (EE / 64);
  float s = 0.f;
  for (int j = 0; j < EE / 64; j++) {
    float h = row[j * 64 + lane];
    s += h;
    unsigned long long m = __ballot(h != 0.0f);
    if (lane == 0) mrow[j] = m;
  }
  for (int off = 32; off; off >>= 1) s += __shfl_down(s, off);
  if (lane == 0) {
    float rwr = rw[r];
    dvs[wave] = rwr * rsqrtf(rwr * s + 1e-8f);
  }
}

// ---- column counts via ballot bit-transpose: wave handles 64 rows x one 64-col word ----
__global__ void k_de_pop(const unsigned long long* __restrict__ mask, float* __restrict__ de_acc) {
  int wid = threadIdx.x >> 6, lane = threadIdx.x & 63;
  int wcol = blockIdx.x, r = blockIdx.z;
  int n0 = (blockIdx.y << 8) + (wid << 6);
  unsigned long long w = mask[(size_t)(r * NN + n0 + lane) * (EE / 64) + wcol];
  float cnt = 0.f;
#pragma unroll
  for (int b = 0; b < 64; b++) {
    unsigned long long m = __ballot(((w >> b) & 1ULL) != 0);
    if (lane == b) cnt = (float)__popcll(m);
  }
  atomicAdd(&de_acc[r * EE + (wcol << 6) + lane], cnt);
}

// ---- finalize in place: de[i] = rsqrt(rw*count+eps) ----
__global__ void k_de_fin(const float* __restrict__ rw, float* __restrict__ de) {
  int i = blockIdx.x * 256 + threadIdx.x;
  int r = i / EE;
  de[i] = rsqrtf(rw[r] * de[i] + 1e-8f);
}

// ---- build theta[r][n][e] bf16 and thetaT[r][e][n] from bitmask ----
__global__ void k_build_theta_bits(const unsigned long long* __restrict__ mask,
                                   const float* __restrict__ dvs, const float* __restrict__ de,
                                   unsigned short* __restrict__ theta, unsigned short* __restrict__ thetaT) {
  __shared__ unsigned short tile[64][65];
  int r = blockIdx.z;
  int e0 = blockIdx.x * 64, n0 = blockIdx.y * 64;
  int tr = threadIdx.x >> 4, tc = threadIdx.x & 15;
  float de0 = de[r * EE + e0 + tc * 4 + 0];
  float de1 = de[r * EE + e0 + tc * 4 + 1];
  float de2 = de[r * EE + e0 + tc * 4 + 2];
  float de3 = de[r * EE + e0 + tc * 4 + 3];
  int wcol = e0 >> 6;
#pragma unroll
  for (int i = 0; i < 4; i++) {
    int n = n0 + tr + 16 * i;
    unsigned long long w = mask[((size_t)r * NN + n) * (EE / 64) + wcol];
    float d = dvs[r * NN + n];
    unsigned short b0 = ((w >> (tc * 4 + 0)) & 1) ? f2b(d * de0) : 0;
    unsigned short b1 = ((w >> (tc * 4 + 1)) & 1) ? f2b(d * de1) : 0;
    unsigned short b2 = ((w >> (tc * 4 + 2)) & 1) ? f2b(d * de2) : 0;
    unsigned short b3 = ((w >> (tc * 4 + 3)) & 1) ? f2b(d * de3) : 0;
    ushort4 o; o.x = b0; o.y = b1; o.z = b2; o.w = b3;
    *(ushort4*)(theta + ((size_t)r * NN + n) * EE + e0 + tc * 4) = o;
    tile[tr + 16 * i][tc * 4 + 0] = b0;
    tile[tr + 16 * i][tc * 4 + 1] = b1;
    tile[tr + 16 * i][tc * 4 + 2] = b2;
    tile[tr + 16 * i][tc * 4 + 3] = b3;
  }
  __syncthreads();
#pragma unroll
  for (int i = 0; i < 4; i++) {
    int e = e0 + tr + 16 * i;
    ushort4 o;
    o.x = tile[tc * 4 + 0][tr + 16 * i];
    o.y = tile[tc * 4 + 1][tr + 16 * i];
    o.z = tile[tc * 4 + 2][tr + 16 * i];
    o.w = tile[tc * 4 + 3][tr + 16 * i];
    *(ushort4*)(thetaT + ((size_t)r * EE + e) * NN + n0 + tc * 4) = o;
  }
}

// ---- f32 [M][C] -> bf16 [C][M] (transpose+convert) ----
__global__ void k_cvtT(const float* __restrict__ src, unsigned short* __restrict__ dst, int M, int C) {
  __shared__ unsigned short tile[64][65];
  int c0 = blockIdx.x * 64, m0 = blockIdx.y * 64;
  int tr = threadIdx.x >> 4, tc = threadIdx.x & 15;
#pragma unroll
  for (int i = 0; i < 4; i++) {
    int m = m0 + tr + 16 * i;
    float4 v = *(const float4*)(src + (size_t)m * C + c0 + tc * 4);
    tile[tr + 16 * i][tc * 4 + 0] = f2b(v.x);
    tile[tr + 16 * i][tc * 4 + 1] = f2b(v.y);
    tile[tr + 16 * i][tc * 4 + 2] = f2b(v.z);
    tile[tr + 16 * i][tc * 4 + 3] = f2b(v.w);
  }
  __syncthreads();
#pragma unroll
  for (int i = 0; i < 4; i++) {
    int c = c0 + tr + 16 * i;
    ushort4 v;
    v.x = tile[tc * 4 + 0][tr + 16 * i];
    v.y = tile[tc * 4 + 1][tr + 16 * i];
    v.z = tile[tc * 4 + 2][tr + 16 * i];
    v.w = tile[tc * 4 + 3][tr + 16 * i];
    *(ushort4*)(dst + (size_t)c * M + m0 + tc * 4) = v;
  }
}

// ---- bf16 [M][C] -> bf16 [C][M] ----
__global__ void k_trz(const unsigned short* __restrict__ src, unsigned short* __restrict__ dst, int M, int C) {
  __shared__ unsigned short tile[64][65];
  int c0 = blockIdx.x * 64, m0 = blockIdx.y * 64;
  int tr = threadIdx.x >> 4, tc = threadIdx.x & 15;
#pragma unroll
  for (int i = 0; i < 4; i++) {
    int m = m0 + tr + 16 * i;
    ushort4 v = *(const ushort4*)(src + (size_t)m * C + c0 + tc * 4);
    tile[tr + 16 * i][tc * 4 + 0] = v.x;
    tile[tr + 16 * i][tc * 4 + 1] = v.y;
    tile[tr + 16 * i][tc * 4 + 2] = v.z;
    tile[tr + 16 * i][tc * 4 + 3] = v.w;
  }
  __syncthreads();
#pragma unroll
  for (int i = 0; i < 4; i++) {
    int c = c0 + tr + 16 * i;
    ushort4 v;
    v.x = tile[tc * 4 + 0][tr + 16 * i];
    v.y = tile[tc * 4 + 1][tr + 16 * i];
    v.z = tile[tc * 4 + 2][tr + 16 * i];
    v.w = tile[tc * 4 + 3][tr + 16 * i];
    *(ushort4*)(dst + (size_t)c * M + m0 + tc * 4) = v;
  }
}

// ---- W1catT[o][r*FF+f] = sig*W1[r][f][o] ----
__global__ void k_wcat(const float* __restrict__ W, const float* __restrict__ sig, int loff, int Fin,
                       unsigned short* __restrict__ WT) {
  int idx = blockIdx.x * 256 + threadIdx.x;
  int o = idx % HDD;
  int f = (idx / HDD) % Fin;
  int r = idx / (HDD * Fin);
  WT[(size_t)o * (RR * Fin) + r * Fin + f] = f2b(sig[loff + r] * W[((size_t)r * Fin + f) * HDD + o]);
}

// ---- WT[r][o][c] = sig*W[r][c][o] ----
__global__ void k_wt(const float* __restrict__ W, const float* __restrict__ sig, int loff,
                     int Cin, int Cout, unsigned short* __restrict__ WT) {
  int idx = blockIdx.x * 256 + threadIdx.x;
  int c = idx % Cin;
  int o = (idx / Cin) % Cout;
  int r = idx / (Cin * Cout);
  WT[idx] = f2b(sig[loff + r] * W[((size_t)r * Cin + c) * Cout + o]);
}

// ---------------- MFMA GEMM, 128x128 tile, BK=64, async staging, partial-store split-K ----------------
// z = zr*SK + kz. Partial: P[z][region], plain f32 stores (NO atomics).
__global__ __launch_bounds__(256) void k_gemm3(
    const unsigned short* __restrict__ A, const unsigned short* __restrict__ BT,
    int K, int SK, int lda, int ldb, long a_rs, long b_rs,
    float* __restrict__ P, long c_ps, int ldc) {
  __shared__ unsigned short Al[8 * 1040];
  __shared__ unsigned short Bl[8 * 1040];
  int tid = threadIdx.x, wid = tid >> 6, lane = tid & 63;
  int m0 = blockIdx.x << 7, n0 = blockIdx.y << 7;
  int z = blockIdx.z, zr = z / SK, kz = z - zr * SK;
  int Kc = K / SK;
  const unsigned short* Ab = A + (size_t)zr * a_rs + (size_t)m0 * lda + (size_t)kz * Kc;
  const unsigned short* Bb = BT + (size_t)zr * b_rs + (size_t)n0 * ldb + (size_t)kz * Kc;
  int wm = (wid >> 1) << 6, wn = (wid & 1) << 6;
  int fm = lane & 15, quad = lane >> 4;
  floatx4 acc[4][4];
#pragma unroll
  for (int i = 0; i < 4; i++)
#pragma unroll
    for (int j = 0; j < 4; j++) acc[i][j] = (floatx4){0.f, 0.f, 0.f, 0.f};
  for (int k0 = 0; k0 < Kc; k0 += 64) {
#pragma unroll
    for (int t = 0; t < 4; t++) {
      int idx = (t << 2) | wid;          // 0..15 covers kg 0..7 x row-half {0,64}
      int kg = idx >> 1, half = (idx & 1) << 6;
      async16(Ab + (size_t)(half + lane) * lda + k0 + kg * 8, &Al[kg * 1040 + half * 8 + lane * 8]);
      async16(Bb + (size_t)(half + lane) * ldb + k0 + kg * 8, &Bl[kg * 1040 + half * 8 + lane * 8]);
    }
    __syncthreads();  // vmcnt(0) drain before s_barrier makes LDS writes visible
#pragma unroll
    for (int ks = 0; ks < 2; ks++) {
      int kgb = ((ks << 2) | quad) * 1040;
      bf16x8 a[4], b[4];
#pragma unroll
      for (int i = 0; i < 4; i++) {
        a[i] = *(const bf16x8*)&Al[kgb + (wm + i * 16 + fm) * 8];
        b[i] = *(const bf16x8*)&Bl[kgb + (wn + i * 16 + fm) * 8];
      }
#pragma unroll
      for (int i = 0; i < 4; i++)
#pragma unroll
        for (int j = 0; j < 4; j++)
          acc[i][j] = __builtin_amdgcn_mfma_f32_16x16x32_bf16(a[i], b[j], acc[i][j], 0, 0, 0);
    }
    __syncthreads();
  }
  float* Cb = P + (size_t)z * c_ps;
#pragma unroll
  for (int mi = 0; mi < 4; mi++)
#pragma unroll
    for (int ni = 0; ni < 4; ni++)
#pragma unroll
      for (int v = 0; v < 4; v++) {
        int row = m0 + wm + mi * 16 + quad * 4 + v;
        int col = n0 + wn + ni * 16 + fm;
        Cb[(size_t)row * ldc + col] = acc[mi][ni][v];
      }
}

// ---- reduce SK partials per zr -> bf16 out[zr][region] (row-major) ----
__global__ void k_red_bf16(const float* __restrict__ P, unsigned short* __restrict__ out,
                           int SK, long region) {
  long i = ((long)blockIdx.x * 256 + threadIdx.x) * 4;
  int zr = blockIdx.y;
  const float* p = P + (size_t)zr * SK * region + i;
  float4 s = *(const float4*)p;
  for (int k = 1; k < SK; k++) {
    float4 v = *(const float4*)(p + (size_t)k * region);
    s.x += v.x; s.y += v.y; s.z += v.z; s.w += v.w;
  }
  ushort4 o; o.x = f2b(s.x); o.y = f2b(s.y); o.z = f2b(s.z); o.w = f2b(s.w);
  *(ushort4*)(out + (size_t)zr * region + i) = o;
}

// ---- reduce SK partials of [M][C] per zr AND transpose -> bf16 outT[zr][C][M] ----
__global__ void k_redT_bf16(const float* __restrict__ P, unsigned short* __restrict__ outT,
                            int SK, int M, int C) {
  __shared__ unsigned short tile[64][65];
  int zr = blockIdx.z;
  long region = (long)M * C;
  const float* p0 = P + (size_t)zr * SK * region;
  int c0 = blockIdx.x * 64, m0 = blockIdx.y * 64;
  int tr = threadIdx.x >> 4, tc = threadIdx.x & 15;
#pragma unroll
  for (int i = 0; i < 4; i++) {
    int m = m0 + tr + 16 * i;
    const float* p = p0 + (size_t)m * C + c0 + tc * 4;
    float4 s = *(const float4*)p;
    for (int k = 1; k < SK; k++) {
      float4 v = *(const float4*)(p + (size_t)k * region);
      s.x += v.x; s.y += v.y; s.z += v.z; s.w += v.w;
    }
    tile[tr + 16 * i][tc * 4 + 0] = f2b(s.x);
    tile[tr + 16 * i][tc * 4 + 1] = f2b(s.y);
    tile[tr + 16 * i][tc * 4 + 2] = f2b(s.z);
    tile[tr + 16 * i][tc * 4 + 3] = f2b(s.w);
  }
  __syncthreads();
  unsigned short* d = outT + (size_t)zr * region;
#pragma unroll
  for (int i = 0; i < 4; i++) {
    int c = c0 + tr + 16 * i;
    ushort4 v;
    v.x = tile[tc * 4 + 0][tr + 16 * i];
    v.y = tile[tc * 4 + 1][tr + 16 * i];
    v.z = tile[tc * 4 + 2][tr + 16 * i];
    v.w = tile[tc * 4 + 3][tr + 16 * i];
    *(ushort4*)(d + (size_t)c * M + m0 + tc * 4) = v;
  }
}

// ---- reduce SK partials per r of [NN][FF] -> Hcat[n][r*FF+f] bf16 ----
__global__ void k_red_hcat(const float* __restrict__ P, unsigned short* __restrict__ out, int SK) {
  long i = ((long)blockIdx.x * 256 + threadIdx.x) * 4;
  int r = blockIdx.y;
  const float* p = P + (size_t)r * SK * (NN * FF) + i;
  float4 s = *(const float4*)p;
  for (int k = 1; k < SK; k++) {
    float4 v = *(const float4*)(p + (size_t)k * (NN * FF));
    s.x += v.x; s.y += v.y; s.z += v.z; s.w += v.w;
  }
  long n = i >> 7;
  int f = (int)(i & 127);
  ushort4 o; o.x = f2b(s.x); o.y = f2b(s.y); o.z = f2b(s.z); o.w = f2b(s.w);
  *(ushort4*)(out + n * (RR * FF) + r * FF + f) = o;
}

// ---- reduce Z partials of [NN][HDD] -> convout f32 + fused column stats ----
__global__ void k_red_stats(const float* __restrict__ P, float* __restrict__ out,
                            float* __restrict__ cs, float* __restrict__ cs2, int Z) {
  int col = threadIdx.x;
  int row0 = blockIdx.x * 16;
  float s = 0.f, s2 = 0.f;
  for (int i = 0; i < 16; i++) {
    long idx = (long)(row0 + i) * HDD + col;
    float v = 0.f;
    for (int z = 0; z < Z; z++) v += P[(size_t)z * ((long)NN * HDD) + idx];
    out[idx] = v;
    s += v; s2 += v * v;
  }
  atomicAdd(&cs[col], s);
  atomicAdd(&cs2[col], s2);
}

// ---- final: d_out = X + b3 + sum_Z P ----
__global__ void k_red_out(const float* __restrict__ P, const float* __restrict__ X,
                          const float* __restrict__ b3, float* __restrict__ out, int Z) {
  long i = ((long)blockIdx.x * 256 + threadIdx.x) * 4;
  int f = (int)(i & 127);
  float4 s = *(const float4*)(X + i);
  s.x += b3[f]; s.y += b3[f + 1]; s.z += b3[f + 2]; s.w += b3[f + 3];
  for (int z = 0; z < Z; z++) {
    float4 v = *(const float4*)(P + (size_t)z * (NN * FF) + i);
    s.x += v.x; s.y += v.y; s.z += v.z; s.w += v.w;
  }
  *(float4*)(out + i) = s;
}

// ---- BN (batch stats) -> LN -> ELU -> bf16 [NN][HDD] ----
__global__ void k_bnlnelu(const float* __restrict__ x, const float* __restrict__ cs, const float* __restrict__ cs2,
                          const float* __restrict__ bg, const float* __restrict__ bb,
                          const float* __restrict__ lg, const float* __restrict__ lb,
                          unsigned short* __restrict__ out) {
  int wid = threadIdx.x >> 6, lane = threadIdx.x & 63;
  int n = blockIdx.x * 4 + wid;
  float y[4];
  float m = 0.f;
#pragma unroll
  for (int j = 0; j < 4; j++) {
    int c = lane + 64 * j;
    float mu = cs[c] * (1.0f / NN);
    float var = cs2[c] * (1.0f / NN) - mu * mu;
    float xv = x[(size_t)n * HDD + c];
    y[j] = (xv - mu) * rsqrtf(var + 1e-5f) * bg[c] + bb[c];
    m += y[j];
  }
  for (int off = 32; off; off >>= 1) m += __shfl_down(m, off);
  m = __shfl(m, 0) * (1.0f / HDD);
  float var = 0.f;
#pragma unroll
  for (int j = 0; j < 4; j++) { float d = y[j] - m; var += d * d; }
  for (int off = 32; off; off >>= 1) var += __shfl_down(var, off);
  var = __shfl(var, 0) * (1.0f / HDD);
  float inv = rsqrtf(var + 1e-5f);
#pragma unroll
  for (int j = 0; j < 4; j++) {
    int c = lane + 64 * j;
    float z = (y[j] - m) * inv * lg[c] + lb[c];
    z = z > 0.f ? z : expm1f(z);
    out[(size_t)n * HDD + c] = f2b(z);
  }
}

extern "C" void kernel_launch(void* const* d_in, const int* in_sizes, int n_in,
                              void* d_out, int out_size, void* d_ws, size_t ws_size,
                              hipStream_t stream) {
  const float* X   = (const float*)d_in[0];
  const float* H   = (const float*)d_in[1];
  const float* W1  = (const float*)d_in[2];
  const float* W2  = (const float*)d_in[3];
  const float* W3  = (const float*)d_in[4];
  const float* imp = (const float*)d_in[5];
  const float* b3  = (const float*)d_in[8];
  const float* bng = (const float*)d_in[9];
  const float* bnb = (const float*)d_in[10];
  const float* lng = (const float*)d_in[11];
  const float* lnb = (const float*)d_in[12];
  const float* rel = (const float*)d_in[13];
  (void)in_sizes; (void)n_in; (void)out_size; (void)ws_size;

  char* w = (char*)d_ws;
  size_t off = 0;
  auto alloc = [&](size_t bytes) -> void* {
    void* p = w + off;
    off += (bytes + 255) & ~(size_t)255;
    return p;
  };
  float* rw   = (float*)alloc(16);
  float* sig  = (float*)alloc(48);
  float* dvs  = (float*)alloc((size_t)RR * NN * 4);
  float* de   = (float*)alloc((size_t)RR * EE * 4);
  float* cs   = (float*)alloc(HDD * 4);
  float* cs2  = (float*)alloc(HDD * 4);
  unsigned long long* mask = (unsigned long long*)alloc((size_t)RR * NN * (EE / 64) * 8);
  unsigned short* theta  = (unsigned short*)alloc((size_t)RR * NN * EE * 2);   // 64MB
  unsigned short* thetaT = (unsigned short*)alloc((size_t)RR * NN * EE * 2);   // 64MB
  float* bufP = (float*)alloc((size_t)16 * NN * HDD * 4);                      // 64MB partials
  unsigned short* bufC = (unsigned short*)alloc((size_t)RR * EE * HDD * 2);    // 4MB bf16
  unsigned short* bufD = (unsigned short*)alloc((size_t)RR * EE * HDD * 2);    // 4MB bf16
  unsigned short* bufE = (unsigned short*)alloc((size_t)RR * EE * HDD * 2);    // 4MB bf16
  float* convout = (float*)alloc((size_t)NN * HDD * 4);                        // 4MB
  unsigned short* Xb  = (unsigned short*)alloc((size_t)NN * HDD * 2);
  unsigned short* XbT = (unsigned short*)alloc((size_t)NN * HDD * 2);
  unsigned short* bufW = (unsigned short*)alloc((size_t)RR * HDD * HDD * 2);   // 512KB

  // ---- prep ----
  k_prep<<<1, 64, 0, stream>>>(rel, imp, rw, sig);
  k_dvmask<<<(RR * NN) / 4, 256, 0, stream>>>(H, rw, dvs, mask);
  hipMemsetAsync(de, 0, (size_t)RR * EE * 4, stream);
  k_de_pop<<<dim3(EE / 64, NN / 256, RR), 256, 0, stream>>>(mask, de);
  k_de_fin<<<(RR * EE) / 256, 256, 0, stream>>>(rw, de);
  k_build_theta_bits<<<dim3(EE / 64, NN / 64, RR), 256, 0, stream>>>(mask, dvs, de, theta, thetaT);
  k_cvtT<<<dim3(FF / 64, NN / 64), 256, 0, stream>>>(X, XbT, NN, FF);  // XbT [128][4096] bf16

  // ---- layer 1 (128 -> 256) ----
  // tT[r][f][e] = sum_n XbT[f][n] thetaT[r][e][n]   M=128,N=2048,K=4096, z=(r,SK8) -> 512 blocks
  k_gemm3<<<dim3(1, EE / 128, RR * 8), 256, 0, stream>>>(
      XbT, thetaT, NN, 8, NN, NN, 0, (long)EE * NN, bufP, (long)FF * EE, EE);
  k_red_bf16<<<dim3((FF * EE) / 1024, RR), 256, 0, stream>>>(bufP, bufC, 8, (long)FF * EE);  // tTb
  // Hcat[n][r*128+f] = sum_e theta[r][n][e] tTb[r][f][e]   M=4096,N=128,K=2048, SK=4 -> 512 blocks
  k_gemm3<<<dim3(NN / 128, 1, RR * 4), 256, 0, stream>>>(
      theta, bufC, EE, 4, EE, EE, (long)NN * EE, (long)FF * EE, bufP, (long)NN * FF, FF);
  k_red_hcat<<<dim3((NN * FF) / 1024, RR), 256, 0, stream>>>(bufP, bufD, 4);  // Hcatb [4096][512]
  k_wcat<<<(RR * FF * HDD) / 256, 256, 0, stream>>>(W1, sig, 0, FF, bufW);
  // convout = Hcatb @ W1cat   M=4096,N=256,K=512, SK=4 -> 256 blocks (b1 dropped: BN-invariant)
  k_gemm3<<<dim3(NN / 128, HDD / 128, 4), 256, 0, stream>>>(
      bufD, bufW, RR * FF, 4, RR * FF, RR * FF, 0, 0, bufP, (long)NN * HDD, HDD);
  hipMemsetAsync(cs, 0, HDD * 4, stream);
  hipMemsetAsync(cs2, 0, HDD * 4, stream);
  k_red_stats<<<NN / 16, 256, 0, stream>>>(bufP, convout, cs, cs2, 4);
  k_bnlnelu<<<NN / 4, 256, 0, stream>>>(convout, cs, cs2, bng, bnb, lng, lnb, Xb);
  k_trz<<<dim3(HDD / 64, NN / 64), 256, 0, stream>>>(Xb, XbT, NN, HDD);

  // ---- layer 2 (256 -> 256) ----
  // t2[re][c] = sum_n thetaT-flat[re][n] h^T[c][n]   M=8192,N=256,K=4096, SK=8 -> 1024 blocks
  k_gemm3<<<dim3(64, HDD / 128, 8), 256, 0, stream>>>(
      thetaT, XbT, NN, 8, NN, NN, 0, 0, bufP, (long)RR * EE * HDD, HDD);
  k_red_bf16<<<dim3((RR * EE * HDD) / 1024, 1), 256, 0, stream>>>(bufP, bufD, 8, (long)RR * EE * HDD);  // t2b
  k_wt<<<(RR * HDD * HDD) / 256, 256, 0, stream>>>(W2, sig, RR, HDD, HDD, bufW);  // W2T [r][o][c]
  // u[r][e][o] = sum_c t2b[r][e][c] W2T[r][o][c]   M=2048,N=256,K=256, SK=2 -> 256 blocks
  k_gemm3<<<dim3(EE / 128, HDD / 128, RR * 2), 256, 0, stream>>>(
      bufD, bufW, HDD, 2, HDD, HDD, (long)EE * HDD, (long)HDD * HDD, bufP, (long)EE * HDD, HDD);
  k_redT_bf16<<<dim3(HDD / 64, EE / 64, RR), 256, 0, stream>>>(bufP, bufE, 2, EE, HDD);  // uTb [r][o][e]
  // convout[n][o] = sum_r sum_e theta[r][n][e] uTb[r][o][e]   M=4096,N=256,K=2048, z=(r,SK4) -> 1024 blocks
  k_gemm3<<<dim3(NN / 128, HDD / 128, RR * 4), 256, 0, stream>>>(
      theta, bufE, EE, 4, EE, EE, (long)NN * EE, (long)HDD * EE, bufP, (long)NN * HDD, HDD);
  hipMemsetAsync(cs, 0, HDD * 4, stream);
  hipMemsetAsync(cs2, 0, HDD * 4, stream);
  k_red_stats<<<NN / 16, 256, 0, stream>>>(bufP, convout, cs, cs2, 16);
  k_bnlnelu<<<NN / 4, 256, 0, stream>>>(convout, cs, cs2, bng + HDD, bnb + HDD, lng + HDD, lnb + HDD, Xb);

  // ---- layer 3 (256 -> 128), W3 applied first ----
  k_wt<<<(RR * HDD * FF) / 256, 256, 0, stream>>>(W3, sig, 2 * RR, HDD, FF, bufW);  // W3T [r][o][c]
  // y[r][n][o] = sum_c Xb[n][c] W3T[r][o][c]   M=4096,N=128,K=256, SK=2 -> 256 blocks
  k_gemm3<<<dim3(NN / 128, 1, RR * 2), 256, 0, stream>>>(
      Xb, bufW, HDD, 2, HDD, HDD, 0, (long)FF * HDD, bufP, (long)NN * FF, FF);
  k_redT_bf16<<<dim3(FF / 64, NN / 64, RR), 256, 0, stream>>>(bufP, bufD, 2, NN, FF);  // yTb [r][f][n]
  // s[r][e][f] = sum_n thetaT[r][e][n] yTb[r][f][n]   M=2048,N=128,K=4096, SK=8 -> 512 blocks
  k_gemm3<<<dim3(EE / 128, 1, RR * 8), 256, 0, stream>>>(
      thetaT, bufD, NN, 8, NN, NN, (long)EE * NN, (long)FF * NN, bufP, (long)EE * FF, FF);
  k_redT_bf16<<<dim3(FF / 64, EE / 64, RR), 256, 0, stream>>>(bufP, bufE, 8, EE, FF);  // sTb [r][f][e]
  // P[z] = theta[r] @ sTb[r] chunks   M=4096,N=128,K=2048, z=(r,SK4) -> 512 blocks
  k_gemm3<<<dim3(NN / 128, 1, RR * 4), 256, 0, stream>>>(
      theta, bufE, EE, 4, EE, EE, (long)NN * EE, (long)FF * EE, bufP, (long)NN * FF, FF);
  // d_out = X + b3 + sum_z P[z]
  k_red_out<<<(NN * FF) / 1024, 256, 0, stream>>>(bufP, X, b3, (float*)d_out, 16);
}

// Round 6
// 593.143 us; speedup vs baseline: 1.1085x; 1.1085x over previous
//
#include <hip/hip_runtime.h>
#include <hip/hip_bf16.h>

#define NN 4096
#define EE 2048
#define RR 4
#define FF 128
#define HDD 256

typedef __attribute__((ext_vector_type(4))) float floatx4;
typedef __attribute__((ext_vector_type(8))) __bf16 bf16x8;

#define AS1 __attribute__((address_space(1)))
#define AS3 __attribute__((address_space(3)))

__device__ __forceinline__ void async16(const void* g, void* l) {
  // global -> LDS direct copy, 16B per lane; LDS dest = wave-uniform base + lane*16
  __builtin_amdgcn_global_load_lds((const AS1 void*)(unsigned long long)(g),
                                   (AS3 void*)(unsigned int)(unsigned long long)(l),
                                   16, 0, 0);
}

__device__ inline unsigned short f2b(float x) {
  unsigned int u = __float_as_uint(x);
  unsigned int r = u + 0x7fffu + ((u >> 16) & 1u);
  return (unsigned short)(r >> 16);
}

// softmax weight for relation r over rel[0..3], computed inline (4 floats, trivial)
__device__ inline float rel_w(const float* rel, int r) {
  float m = fmaxf(fmaxf(rel[0], rel[1]), fmaxf(rel[2], rel[3]));
  float s = 0.f;
#pragma unroll
  for (int i = 0; i < RR; i++) s += expf(rel[i] - m);
  return expf(rel[r] - m) / s;
}

// ---- single pass over H: row sums -> dvs[r][n] = rw*rsqrt(rw*sum+eps), plus 0/1 bitmask ----
__global__ void k_dvmask(const float* __restrict__ H, const float* __restrict__ rel,
                         float* __restrict__ dvs, unsigned long long* __restrict__ mask) {
  int wave = (blockIdx.x << 2) | (threadIdx.x >> 6);  // = r*NN + n
  int lane = threadIdx.x & 63;
  int r = wave >> 12;
  const float* row = H + (size_t)wave * EE;
  unsigned long long* mrow = mask + (size_t)wave * (EE / 64);
  float s = 0.f;
  for (int j = 0; j < EE / 64; j++) {
    float h = row[j * 64 + lane];
    s += h;
    unsigned long long m = __ballot(h != 0.0f);
    if (lane == 0) mrow[j] = m;
  }
  for (int off = 32; off; off >>= 1) s += __shfl_down(s, off);
  if (lane == 0) {
    float rwr = rel_w(rel, r);
    dvs[wave] = rwr * rsqrtf(rwr * s + 1e-8f);
  }
}

// ---- column counts via ballot bit-transpose: wave handles 64 rows x one 64-col word ----
__global__ void k_de_pop(const unsigned long long* __restrict__ mask, float* __restrict__ de_acc) {
  int wid = threadIdx.x >> 6, lane = threadIdx.x & 63;
  int wcol = blockIdx.x, r = blockIdx.z;
  int n0 = (blockIdx.y << 8) + (wid << 6);
  unsigned long long w = mask[(size_t)(r * NN + n0 + lane) * (EE / 64) + wcol];
  float cnt = 0.f;
#pragma unroll
  for (int b = 0; b < 64; b++) {
    unsigned long long m = __ballot(((w >> b) & 1ULL) != 0);
    if (lane == b) cnt = (float)__popcll(m);
  }
  atomicAdd(&de_acc[r * EE + (wcol << 6) + lane], cnt);
}

// ---- build theta[r][n][e] bf16 and thetaT[r][e][n]; de finalize (rsqrt) fused inline ----
__global__ void k_build_theta_bits(const unsigned long long* __restrict__ mask,
                                   const float* __restrict__ dvs, const float* __restrict__ decnt,
                                   const float* __restrict__ rel,
                                   unsigned short* __restrict__ theta, unsigned short* __restrict__ thetaT) {
  __shared__ unsigned short tile[64][65];
  int r = blockIdx.z;
  int e0 = blockIdx.x * 64, n0 = blockIdx.y * 64;
  int tr = threadIdx.x >> 4, tc = threadIdx.x & 15;
  float rwr = rel_w(rel, r);
  float de0 = rsqrtf(rwr * decnt[r * EE + e0 + tc * 4 + 0] + 1e-8f);
  float de1 = rsqrtf(rwr * decnt[r * EE + e0 + tc * 4 + 1] + 1e-8f);
  float de2 = rsqrtf(rwr * decnt[r * EE + e0 + tc * 4 + 2] + 1e-8f);
  float de3 = rsqrtf(rwr * decnt[r * EE + e0 + tc * 4 + 3] + 1e-8f);
  int wcol = e0 >> 6;
#pragma unroll
  for (int i = 0; i < 4; i++) {
    int n = n0 + tr + 16 * i;
    unsigned long long w = mask[((size_t)r * NN + n) * (EE / 64) + wcol];
    float d = dvs[r * NN + n];
    unsigned short b0 = ((w >> (tc * 4 + 0)) & 1) ? f2b(d * de0) : 0;
    unsigned short b1 = ((w >> (tc * 4 + 1)) & 1) ? f2b(d * de1) : 0;
    unsigned short b2 = ((w >> (tc * 4 + 2)) & 1) ? f2b(d * de2) : 0;
    unsigned short b3 = ((w >> (tc * 4 + 3)) & 1) ? f2b(d * de3) : 0;
    ushort4 o; o.x = b0; o.y = b1; o.z = b2; o.w = b3;
    *(ushort4*)(theta + ((size_t)r * NN + n) * EE + e0 + tc * 4) = o;
    tile[tr + 16 * i][tc * 4 + 0] = b0;
    tile[tr + 16 * i][tc * 4 + 1] = b1;
    tile[tr + 16 * i][tc * 4 + 2] = b2;
    tile[tr + 16 * i][tc * 4 + 3] = b3;
  }
  __syncthreads();
#pragma unroll
  for (int i = 0; i < 4; i++) {
    int e = e0 + tr + 16 * i;
    ushort4 o;
    o.x = tile[tc * 4 + 0][tr + 16 * i];
    o.y = tile[tc * 4 + 1][tr + 16 * i];
    o.z = tile[tc * 4 + 2][tr + 16 * i];
    o.w = tile[tc * 4 + 3][tr + 16 * i];
    *(ushort4*)(thetaT + ((size_t)r * EE + e) * NN + n0 + tc * 4) = o;
  }
}

// ---- f32 [M][C] -> bf16 [C][M] (transpose+convert) ----
__global__ void k_cvtT(const float* __restrict__ src, unsigned short* __restrict__ dst, int M, int C) {
  __shared__ unsigned short tile[64][65];
  int c0 = blockIdx.x * 64, m0 = blockIdx.y * 64;
  int tr = threadIdx.x >> 4, tc = threadIdx.x & 15;
#pragma unroll
  for (int i = 0; i < 4; i++) {
    int m = m0 + tr + 16 * i;
    float4 v = *(const float4*)(src + (size_t)m * C + c0 + tc * 4);
    tile[tr + 16 * i][tc * 4 + 0] = f2b(v.x);
    tile[tr + 16 * i][tc * 4 + 1] = f2b(v.y);
    tile[tr + 16 * i][tc * 4 + 2] = f2b(v.z);
    tile[tr + 16 * i][tc * 4 + 3] = f2b(v.w);
  }
  __syncthreads();
#pragma unroll
  for (int i = 0; i < 4; i++) {
    int c = c0 + tr + 16 * i;
    ushort4 v;
    v.x = tile[tc * 4 + 0][tr + 16 * i];
    v.y = tile[tc * 4 + 1][tr + 16 * i];
    v.z = tile[tc * 4 + 2][tr + 16 * i];
    v.w = tile[tc * 4 + 3][tr + 16 * i];
    *(ushort4*)(dst + (size_t)c * M + m0 + tc * 4) = v;
  }
}

// ---- bf16 [M][C] -> bf16 [C][M] ----
__global__ void k_trz(const unsigned short* __restrict__ src, unsigned short* __restrict__ dst, int M, int C) {
  __shared__ unsigned short tile[64][65];
  int c0 = blockIdx.x * 64, m0 = blockIdx.y * 64;
  int tr = threadIdx.x >> 4, tc = threadIdx.x & 15;
#pragma unroll
  for (int i = 0; i < 4; i++) {
    int m = m0 + tr + 16 * i;
    ushort4 v = *(const ushort4*)(src + (size_t)m * C + c0 + tc * 4);
    tile[tr + 16 * i][tc * 4 + 0] = v.x;
    tile[tr + 16 * i][tc * 4 + 1] = v.y;
    tile[tr + 16 * i][tc * 4 + 2] = v.z;
    tile[tr + 16 * i][tc * 4 + 3] = v.w;
  }
  __syncthreads();
#pragma unroll
  for (int i = 0; i < 4; i++) {
    int c = c0 + tr + 16 * i;
    ushort4 v;
    v.x = tile[tc * 4 + 0][tr + 16 * i];
    v.y = tile[tc * 4 + 1][tr + 16 * i];
    v.z = tile[tc * 4 + 2][tr + 16 * i];
    v.w = tile[tc * 4 + 3][tr + 16 * i];
    *(ushort4*)(dst + (size_t)c * M + m0 + tc * 4) = v;
  }
}

// ---- W1catT[o][r*FF+f] = sigmoid(imp[loff+r])*W1[r][f][o] ----
__global__ void k_wcat(const float* __restrict__ W, const float* __restrict__ imp, int loff, int Fin,
                       unsigned short* __restrict__ WT) {
  int idx = blockIdx.x * 256 + threadIdx.x;
  int o = idx % HDD;
  int f = (idx / HDD) % Fin;
  int r = idx / (HDD * Fin);
  float sg = 1.0f / (1.0f + expf(-imp[loff + r]));
  WT[(size_t)o * (RR * Fin) + r * Fin + f] = f2b(sg * W[((size_t)r * Fin + f) * HDD + o]);
}

// ---- WT[r][o][c] = sigmoid(imp[loff+r])*W[r][c][o] ----
__global__ void k_wt(const float* __restrict__ W, const float* __restrict__ imp, int loff,
                     int Cin, int Cout, unsigned short* __restrict__ WT) {
  int idx = blockIdx.x * 256 + threadIdx.x;
  int c = idx % Cin;
  int o = (idx / Cin) % Cout;
  int r = idx / (Cin * Cout);
  float sg = 1.0f / (1.0f + expf(-imp[loff + r]));
  WT[idx] = f2b(sg * W[((size_t)r * Cin + c) * Cout + o]);
}

// ---------------- MFMA GEMM, 128x128 tile, BK=64, async staging, partial-store split-K ----------------
// z = zr*SK + kz. Partial: P[z][region], plain f32 stores (NO atomics).
__global__ __launch_bounds__(256) void k_gemm3(
    const unsigned short* __restrict__ A, const unsigned short* __restrict__ BT,
    int K, int SK, int lda, int ldb, long a_rs, long b_rs,
    float* __restrict__ P, long c_ps, int ldc) {
  __shared__ unsigned short Al[8 * 1040];
  __shared__ unsigned short Bl[8 * 1040];
  int tid = threadIdx.x, wid = tid >> 6, lane = tid & 63;
  int m0 = blockIdx.x << 7, n0 = blockIdx.y << 7;
  int z = blockIdx.z, zr = z / SK, kz = z - zr * SK;
  int Kc = K / SK;
  const unsigned short* Ab = A + (size_t)zr * a_rs + (size_t)m0 * lda + (size_t)kz * Kc;
  const unsigned short* Bb = BT + (size_t)zr * b_rs + (size_t)n0 * ldb + (size_t)kz * Kc;
  int wm = (wid >> 1) << 6, wn = (wid & 1) << 6;
  int fm = lane & 15, quad = lane >> 4;
  floatx4 acc[4][4];
#pragma unroll
  for (int i = 0; i < 4; i++)
#pragma unroll
    for (int j = 0; j < 4; j++) acc[i][j] = (floatx4){0.f, 0.f, 0.f, 0.f};
  for (int k0 = 0; k0 < Kc; k0 += 64) {
#pragma unroll
    for (int t = 0; t < 4; t++) {
      int idx = (t << 2) | wid;          // 0..15 covers kg 0..7 x row-half {0,64}
      int kg = idx >> 1, half = (idx & 1) << 6;
      async16(Ab + (size_t)(half + lane) * lda + k0 + kg * 8, &Al[kg * 1040 + half * 8 + lane * 8]);
      async16(Bb + (size_t)(half + lane) * ldb + k0 + kg * 8, &Bl[kg * 1040 + half * 8 + lane * 8]);
    }
    __syncthreads();  // vmcnt(0) drain before s_barrier makes LDS writes visible
#pragma unroll
    for (int ks = 0; ks < 2; ks++) {
      int kgb = ((ks << 2) | quad) * 1040;
      bf16x8 a[4], b[4];
#pragma unroll
      for (int i = 0; i < 4; i++) {
        a[i] = *(const bf16x8*)&Al[kgb + (wm + i * 16 + fm) * 8];
        b[i] = *(const bf16x8*)&Bl[kgb + (wn + i * 16 + fm) * 8];
      }
#pragma unroll
      for (int i = 0; i < 4; i++)
#pragma unroll
        for (int j = 0; j < 4; j++)
          acc[i][j] = __builtin_amdgcn_mfma_f32_16x16x32_bf16(a[i], b[j], acc[i][j], 0, 0, 0);
    }
    __syncthreads();
  }
  float* Cb = P + (size_t)z * c_ps;
#pragma unroll
  for (int mi = 0; mi < 4; mi++)
#pragma unroll
    for (int ni = 0; ni < 4; ni++)
#pragma unroll
      for (int v = 0; v < 4; v++) {
        int row = m0 + wm + mi * 16 + quad * 4 + v;
        int col = n0 + wn + ni * 16 + fm;
        Cb[(size_t)row * ldc + col] = acc[mi][ni][v];
      }
}

// ---- reduce SK partials per zr -> bf16 out[zr][region] (row-major) ----
__global__ void k_red_bf16(const float* __restrict__ P, unsigned short* __restrict__ out,
                           int SK, long region) {
  long i = ((long)blockIdx.x * 256 + threadIdx.x) * 4;
  int zr = blockIdx.y;
  const float* p = P + (size_t)zr * SK * region + i;
  float4 s = *(const float4*)p;
  for (int k = 1; k < SK; k++) {
    float4 v = *(const float4*)(p + (size_t)k * region);
    s.x += v.x; s.y += v.y; s.z += v.z; s.w += v.w;
  }
  ushort4 o; o.x = f2b(s.x); o.y = f2b(s.y); o.z = f2b(s.z); o.w = f2b(s.w);
  *(ushort4*)(out + (size_t)zr * region + i) = o;
}

// ---- reduce SK partials of [M][C] per zr AND transpose -> bf16 outT[zr][C][M] ----
__global__ void k_redT_bf16(const float* __restrict__ P, unsigned short* __restrict__ outT,
                            int SK, int M, int C) {
  __shared__ unsigned short tile[64][65];
  int zr = blockIdx.z;
  long region = (long)M * C;
  const float* p0 = P + (size_t)zr * SK * region;
  int c0 = blockIdx.x * 64, m0 = blockIdx.y * 64;
  int tr = threadIdx.x >> 4, tc = threadIdx.x & 15;
#pragma unroll
  for (int i = 0; i < 4; i++) {
    int m = m0 + tr + 16 * i;
    const float* p = p0 + (size_t)m * C + c0 + tc * 4;
    float4 s = *(const float4*)p;
    for (int k = 1; k < SK; k++) {
      float4 v = *(const float4*)(p + (size_t)k * region);
      s.x += v.x; s.y += v.y; s.z += v.z; s.w += v.w;
    }
    tile[tr + 16 * i][tc * 4 + 0] = f2b(s.x);
    tile[tr + 16 * i][tc * 4 + 1] = f2b(s.y);
    tile[tr + 16 * i][tc * 4 + 2] = f2b(s.z);
    tile[tr + 16 * i][tc * 4 + 3] = f2b(s.w);
  }
  __syncthreads();
  unsigned short* d = outT + (size_t)zr * region;
#pragma unroll
  for (int i = 0; i < 4; i++) {
    int c = c0 + tr + 16 * i;
    ushort4 v;
    v.x = tile[tc * 4 + 0][tr + 16 * i];
    v.y = tile[tc * 4 + 1][tr + 16 * i];
    v.z = tile[tc * 4 + 2][tr + 16 * i];
    v.w = tile[tc * 4 + 3][tr + 16 * i];
    *(ushort4*)(d + (size_t)c * M + m0 + tc * 4) = v;
  }
}

// ---- reduce SK partials per r of [NN][FF] -> Hcat[n][r*FF+f] bf16 ----
__global__ void k_red_hcat(const float* __restrict__ P, unsigned short* __restrict__ out, int SK) {
  long i = ((long)blockIdx.x * 256 + threadIdx.x) * 4;
  int r = blockIdx.y;
  const float* p = P + (size_t)r * SK * (NN * FF) + i;
  float4 s = *(const float4*)p;
  for (int k = 1; k < SK; k++) {
    float4 v = *(const float4*)(p + (size_t)k * (NN * FF));
    s.x += v.x; s.y += v.y; s.z += v.z; s.w += v.w;
  }
  long n = i >> 7;
  int f = (int)(i & 127);
  ushort4 o; o.x = f2b(s.x); o.y = f2b(s.y); o.z = f2b(s.z); o.w = f2b(s.w);
  *(ushort4*)(out + n * (RR * FF) + r * FF + f) = o;
}

// ---- reduce Z partials -> f32 out ----
__global__ void k_red_f32(const float* __restrict__ P, float* __restrict__ out, int Z, long region) {
  long i = ((long)blockIdx.x * 256 + threadIdx.x) * 4;
  float4 s = *(const float4*)(P + i);
  for (int z = 1; z < Z; z++) {
    float4 v = *(const float4*)(P + (size_t)z * region + i);
    s.x += v.x; s.y += v.y; s.z += v.z; s.w += v.w;
  }
  *(float4*)(out + i) = s;
}

// ---- column stats over [NN][HDD] f32 ----
__global__ void k_colstats(const float* __restrict__ x, float* __restrict__ cs, float* __restrict__ cs2) {
  int col = threadIdx.x;
  int row0 = blockIdx.y * 64;
  float s = 0.f, s2 = 0.f;
  for (int i = 0; i < 64; i++) {
    float v = x[(size_t)(row0 + i) * HDD + col];
    s += v; s2 += v * v;
  }
  atomicAdd(&cs[col], s);
  atomicAdd(&cs2[col], s2);
}

// ---- final: d_out = X + b3 + sum_Z P ----
__global__ void k_red_out(const float* __restrict__ P, const float* __restrict__ X,
                          const float* __restrict__ b3, float* __restrict__ out, int Z) {
  long i = ((long)blockIdx.x * 256 + threadIdx.x) * 4;
  int f = (int)(i & 127);
  float4 s = *(const float4*)(X + i);
  s.x += b3[f]; s.y += b3[f + 1]; s.z += b3[f + 2]; s.w += b3[f + 3];
  for (int z = 0; z < Z; z++) {
    float4 v = *(const float4*)(P + (size_t)z * (NN * FF) + i);
    s.x += v.x; s.y += v.y; s.z += v.z; s.w += v.w;
  }
  *(float4*)(out + i) = s;
}

// ---- BN (batch stats) -> LN -> ELU -> bf16 [NN][HDD] ----
__global__ void k_bnlnelu(const float* __restrict__ x, const float* __restrict__ cs, const float* __restrict__ cs2,
                          const float* __restrict__ bg, const float* __restrict__ bb,
                          const float* __restrict__ lg, const float* __restrict__ lb,
                          unsigned short* __restrict__ out) {
  int wid = threadIdx.x >> 6, lane = threadIdx.x & 63;
  int n = blockIdx.x * 4 + wid;
  float y[4];
  float m = 0.f;
#pragma unroll
  for (int j = 0; j < 4; j++) {
    int c = lane + 64 * j;
    float mu = cs[c] * (1.0f / NN);
    float var = cs2[c] * (1.0f / NN) - mu * mu;
    float xv = x[(size_t)n * HDD + c];
    y[j] = (xv - mu) * rsqrtf(var + 1e-5f) * bg[c] + bb[c];
    m += y[j];
  }
  for (int off = 32; off; off >>= 1) m += __shfl_down(m, off);
  m = __shfl(m, 0) * (1.0f / HDD);
  float var = 0.f;
#pragma unroll
  for (int j = 0; j < 4; j++) { float d = y[j] - m; var += d * d; }
  for (int off = 32; off; off >>= 1) var += __shfl_down(var, off);
  var = __shfl(var, 0) * (1.0f / HDD);
  float inv = rsqrtf(var + 1e-5f);
#pragma unroll
  for (int j = 0; j < 4; j++) {
    int c = lane + 64 * j;
    float z = (y[j] - m) * inv * lg[c] + lb[c];
    z = z > 0.f ? z : expm1f(z);
    out[(size_t)n * HDD + c] = f2b(z);
  }
}

extern "C" void kernel_launch(void* const* d_in, const int* in_sizes, int n_in,
                              void* d_out, int out_size, void* d_ws, size_t ws_size,
                              hipStream_t stream) {
  const float* X   = (const float*)d_in[0];
  const float* H   = (const float*)d_in[1];
  const float* W1  = (const float*)d_in[2];
  const float* W2  = (const float*)d_in[3];
  const float* W3  = (const float*)d_in[4];
  const float* imp = (const float*)d_in[5];
  const float* b3  = (const float*)d_in[8];
  const float* bng = (const float*)d_in[9];
  const float* bnb = (const float*)d_in[10];
  const float* lng = (const float*)d_in[11];
  const float* lnb = (const float*)d_in[12];
  const float* rel = (const float*)d_in[13];
  (void)in_sizes; (void)n_in; (void)out_size; (void)ws_size;

  char* w = (char*)d_ws;
  size_t off = 0;
  auto alloc = [&](size_t bytes) -> void* {
    void* p = w + off;
    off += (bytes + 255) & ~(size_t)255;
    return p;
  };
  float* dvs  = (float*)alloc((size_t)RR * NN * 4);
  float* de   = (float*)alloc((size_t)RR * EE * 4);       // raw column counts
  float* cs   = (float*)alloc(2 * HDD * 4);               // [cs | cs2], one memset
  unsigned long long* mask = (unsigned long long*)alloc((size_t)RR * NN * (EE / 64) * 8);
  unsigned short* theta  = (unsigned short*)alloc((size_t)RR * NN * EE * 2);   // 64MB
  unsigned short* thetaT = (unsigned short*)alloc((size_t)RR * NN * EE * 2);   // 64MB
  float* bufP = (float*)alloc((size_t)8 * NN * HDD * 4);                       // 32MB partials
  unsigned short* bufC = (unsigned short*)alloc((size_t)RR * EE * HDD * 2);    // 4MB bf16
  unsigned short* bufD = (unsigned short*)alloc((size_t)RR * EE * HDD * 2);    // 4MB bf16
  unsigned short* bufE = (unsigned short*)alloc((size_t)RR * EE * HDD * 2);    // 4MB bf16
  float* convout = (float*)alloc((size_t)NN * HDD * 4);                        // 4MB
  unsigned short* Xb  = (unsigned short*)alloc((size_t)NN * HDD * 2);
  unsigned short* XbT = (unsigned short*)alloc((size_t)NN * HDD * 2);
  unsigned short* bufW = (unsigned short*)alloc((size_t)RR * HDD * HDD * 2);   // 512KB

  // ---- prep (k_prep folded into consumers; de_fin folded into build_theta) ----
  k_dvmask<<<(RR * NN) / 4, 256, 0, stream>>>(H, rel, dvs, mask);
  hipMemsetAsync(de, 0, (size_t)RR * EE * 4, stream);
  k_de_pop<<<dim3(EE / 64, NN / 256, RR), 256, 0, stream>>>(mask, de);
  k_build_theta_bits<<<dim3(EE / 64, NN / 64, RR), 256, 0, stream>>>(mask, dvs, de, rel, theta, thetaT);
  k_cvtT<<<dim3(FF / 64, NN / 64), 256, 0, stream>>>(X, XbT, NN, FF);  // XbT [128][4096] bf16

  // ---- layer 1 (128 -> 256) ----
  // tT[r][f][e] = sum_n XbT[f][n] thetaT[r][e][n]   M=128,N=2048,K=4096, z=(r,SK8) -> 512 blocks
  k_gemm3<<<dim3(1, EE / 128, RR * 8), 256, 0, stream>>>(
      XbT, thetaT, NN, 8, NN, NN, 0, (long)EE * NN, bufP, (long)FF * EE, EE);
  k_red_bf16<<<dim3((FF * EE) / 1024, RR), 256, 0, stream>>>(bufP, bufC, 8, (long)FF * EE);  // tTb
  // Hcat[n][r*128+f] = sum_e theta[r][n][e] tTb[r][f][e]   M=4096,N=128,K=2048, SK=2 -> 256 blocks
  k_gemm3<<<dim3(NN / 128, 1, RR * 2), 256, 0, stream>>>(
      theta, bufC, EE, 2, EE, EE, (long)NN * EE, (long)FF * EE, bufP, (long)NN * FF, FF);
  k_red_hcat<<<dim3((NN * FF) / 1024, RR), 256, 0, stream>>>(bufP, bufD, 2);  // Hcatb [4096][512]
  k_wcat<<<(RR * FF * HDD) / 256, 256, 0, stream>>>(W1, imp, 0, FF, bufW);
  // convout = Hcatb @ W1cat   M=4096,N=256,K=512, SK=4 -> 256 blocks (b1 dropped: BN-invariant)
  k_gemm3<<<dim3(NN / 128, HDD / 128, 4), 256, 0, stream>>>(
      bufD, bufW, RR * FF, 4, RR * FF, RR * FF, 0, 0, bufP, (long)NN * HDD, HDD);
  hipMemsetAsync(cs, 0, 2 * HDD * 4, stream);
  k_red_f32<<<(NN * HDD) / 1024, 256, 0, stream>>>(bufP, convout, 4, (long)NN * HDD);
  k_colstats<<<dim3(1, NN / 64), 256, 0, stream>>>(convout, cs, cs + HDD);
  k_bnlnelu<<<NN / 4, 256, 0, stream>>>(convout, cs, cs + HDD, bng, bnb, lng, lnb, Xb);
  k_trz<<<dim3(HDD / 64, NN / 64), 256, 0, stream>>>(Xb, XbT, NN, HDD);

  // ---- layer 2 (256 -> 256) ----
  // t2[re][c] = sum_n thetaT-flat[re][n] h^T[c][n]   M=8192,N=256,K=4096, SK=4 -> 512 blocks
  k_gemm3<<<dim3(64, HDD / 128, 4), 256, 0, stream>>>(
      thetaT, XbT, NN, 4, NN, NN, 0, 0, bufP, (long)RR * EE * HDD, HDD);
  k_red_bf16<<<dim3((RR * EE * HDD) / 1024, 1), 256, 0, stream>>>(bufP, bufD, 4, (long)RR * EE * HDD);  // t2b
  k_wt<<<(RR * HDD * HDD) / 256, 256, 0, stream>>>(W2, imp, RR, HDD, HDD, bufW);  // W2T [r][o][c]
  // u[r][e][o] = sum_c t2b[r][e][c] W2T[r][o][c]   M=2048,N=256,K=256, SK=2 -> 256 blocks
  k_gemm3<<<dim3(EE / 128, HDD / 128, RR * 2), 256, 0, stream>>>(
      bufD, bufW, HDD, 2, HDD, HDD, (long)EE * HDD, (long)HDD * HDD, bufP, (long)EE * HDD, HDD);
  k_redT_bf16<<<dim3(HDD / 64, EE / 64, RR), 256, 0, stream>>>(bufP, bufE, 2, EE, HDD);  // uTb [r][o][e]
  // convout[n][o] = sum_r sum_e theta[r][n][e] uTb[r][o][e]   M=4096,N=256,K=2048, z=(r,SK2) -> 512 blocks
  k_gemm3<<<dim3(NN / 128, HDD / 128, RR * 2), 256, 0, stream>>>(
      theta, bufE, EE, 2, EE, EE, (long)NN * EE, (long)HDD * EE, bufP, (long)NN * HDD, HDD);
  hipMemsetAsync(cs, 0, 2 * HDD * 4, stream);
  k_red_f32<<<(NN * HDD) / 1024, 256, 0, stream>>>(bufP, convout, 8, (long)NN * HDD);
  k_colstats<<<dim3(1, NN / 64), 256, 0, stream>>>(convout, cs, cs + HDD);
  k_bnlnelu<<<NN / 4, 256, 0, stream>>>(convout, cs, cs + HDD, bng + HDD, bnb + HDD, lng + HDD, lnb + HDD, Xb);

  // ---- layer 3 (256 -> 128), W3 applied first ----
  k_wt<<<(RR * HDD * FF) / 256, 256, 0, stream>>>(W3, imp, 2 * RR, HDD, FF, bufW);  // W3T [r][o][c]
  // y[r][n][o] = sum_c Xb[n][c] W3T[r][o][c]   M=4096,N=128,K=256, SK=2 -> 256 blocks
  k_gemm3<<<dim3(NN / 128, 1, RR * 2), 256, 0, stream>>>(
      Xb, bufW, HDD, 2, HDD, HDD, 0, (long)FF * HDD, bufP, (long)NN * FF, FF);
  k_redT_bf16<<<dim3(FF / 64, NN / 64, RR), 256, 0, stream>>>(bufP, bufD, 2, NN, FF);  // yTb [r][f][n]
  // s[r][e][f] = sum_n thetaT[r][e][n] yTb[r][f][n]   M=2048,N=128,K=4096, SK=4 -> 256 blocks
  k_gemm3<<<dim3(EE / 128, 1, RR * 4), 256, 0, stream>>>(
      thetaT, bufD, NN, 4, NN, NN, (long)EE * NN, (long)FF * NN, bufP, (long)EE * FF, FF);
  k_redT_bf16<<<dim3(FF / 64, EE / 64, RR), 256, 0, stream>>>(bufP, bufE, 4, EE, FF);  // sTb [r][f][e]
  // P[z] = theta[r] @ sTb[r] chunks   M=4096,N=128,K=2048, z=(r,SK2) -> 256 blocks
  k_gemm3<<<dim3(NN / 128, 1, RR * 2), 256, 0, stream>>>(
      theta, bufE, EE, 2, EE, EE, (long)NN * EE, (long)FF * EE, bufP, (long)NN * FF, FF);
  // d_out = X + b3 + sum_z P[z]
  k_red_out<<<(NN * FF) / 1024, 256, 0, stream>>>(bufP, X, b3, (float*)d_out, 8);
}